// Round 11
// baseline (131.161 us; speedup 1.0000x reference)
//
#include <hip/hip_runtime.h>
#include <math.h>

namespace {

typedef __attribute__((ext_vector_type(8))) __fp16 f16x8;
typedef __attribute__((ext_vector_type(4))) float f32x4;
typedef __attribute__((ext_vector_type(2))) float f32x2;
typedef __attribute__((ext_vector_type(2))) unsigned u32x2;

constexpr int IN_DIM = 128;
constexpr int EFF    = 130 * 16;   // W1 node stride (floats)
constexpr int NODES  = 255;
constexpr int TS     = 64;         // samples per block (4 MFMA N-tiles per wave)
constexpr int BLOCK  = 256;
constexpr int NC     = 10;

// ---- prep: W1[:, :128, :] -> MFMA fragment layout, fp16 (single product) ----
// frag element (n, t, lane l, j): W[k = t*32 + (l>>4)*8 + j][hid = l&15]
__global__ __launch_bounds__(256) void prep_w1(const float* __restrict__ W1,
                                               f16x8* __restrict__ wfrag) {
    __shared__ float xs[IN_DIM * 16];      // 8 KB: rows 0..127 of this node
    const int n = blockIdx.x, tid = threadIdx.x;
    const float4* src = (const float4*)(W1 + (size_t)n * EFF);
    ((float4*)xs)[tid]       = src[tid];
    ((float4*)xs)[tid + 256] = src[tid + 256];
    __syncthreads();
    const int l = tid & 63, t = tid >> 6;
    const int k0 = t * 32 + (l >> 4) * 8, hid = l & 15;
    f16x8 hv;
    #pragma unroll
    for (int j = 0; j < 8; ++j)
        hv[j] = (__fp16)xs[(k0 + j) * 16 + hid];   // RNE
    wfrag[(n * 4 + t) * 64 + l] = hv;
}

__device__ __forceinline__ void loadW(const f16x8* __restrict__ wfrag, int n, int l,
                                      f16x8 (&w)[4]) {
    const f16x8* wp = wfrag + (size_t)n * 256 + l;
    #pragma unroll
    for (int t = 0; t < 4; ++t) w[t] = wp[t * 64];
}

__device__ __forceinline__ void mfma16(const f16x8 (&w)[4], const f16x8 (&xh)[4][4],
                                       f32x4 (&acc)[4]) {
    #pragma unroll
    for (int t = 0; t < 4; ++t)
        #pragma unroll
        for (int mt = 0; mt < 4; ++mt)
            acc[mt] = __builtin_amdgcn_mfma_f32_16x16x32_f16(w[t], xh[t][mt], acc[mt], 0, 0, 0);
}

// ---- cross-lane half-swaps on the VALU pipe (R23, kept: fewer DS ops) ----
__device__ __forceinline__ float swap32f(float v, bool hi32) {
#if __has_builtin(__builtin_amdgcn_permlane32_swap)
    u32x2 r = __builtin_amdgcn_permlane32_swap(__float_as_uint(v), __float_as_uint(v),
                                               false, false);
    return __uint_as_float(hi32 ? r[0] : r[1]);
#else
    (void)hi32;
    return __shfl_xor(v, 32);
#endif
}

__device__ __forceinline__ float swap16f(float v, bool hi16) {
#if __has_builtin(__builtin_amdgcn_permlane16_swap)
    u32x2 r = __builtin_amdgcn_permlane16_swap(__float_as_uint(v), __float_as_uint(v),
                                               false, false);
    return __uint_as_float(hi16 ? r[0] : r[1]);
#else
    (void)hi16;
    return __shfl_xor(v, 16);
#endif
}

// R26: packed-FP32 epilogue. The combine+dot pairs naturally over r:
// acc[mt] is an MFMA accumulator quad (4 consecutive aligned VGPRs ->
// {r0,r1}/{r2,r3} are aligned pairs) and wp/wg/w2 are dwordx4 loads
// (consecutive). float2 elementwise fma/max lets the backend select
// v_pk_fma_f32 / v_pk_max_f32 (VOP3P), halving the epilogue's VALU issue
// (~64 -> ~36 insts per chain). par/gp broadcasts are op_sel-free.
// Only the 4-term dot's association changes: (r0+r2)+(r1+r3) — <=1 ulp.
__device__ __forceinline__ float epi_score(
    const f32x4 (&acc)[4], const float4& w2q, const float4& wpq, const float4& wgq,
    const float (&par)[4], const float (&gp)[4], float b2v, int quad)
{
    const f32x2 wp01 = {wpq.x, wpq.y}, wp23 = {wpq.z, wpq.w};
    const f32x2 wg01 = {wgq.x, wgq.y}, wg23 = {wgq.z, wgq.w};
    const f32x2 w201 = {w2q.x, w2q.y}, w223 = {w2q.z, w2q.w};
    const f32x2 zero2 = {0.0f, 0.0f};
    float p4[4];
    #pragma unroll
    for (int mt = 0; mt < 4; ++mt) {
        const f32x2 par2 = {par[mt], par[mt]};
        const f32x2 gp2  = {gp[mt], gp[mt]};
        const f32x2 a01  = {acc[mt][0], acc[mt][1]};
        const f32x2 a23  = {acc[mt][2], acc[mt][3]};
        f32x2 h01 = __builtin_elementwise_fma(par2, wp01,
                      __builtin_elementwise_fma(gp2, wg01, a01));
        f32x2 h23 = __builtin_elementwise_fma(par2, wp23,
                      __builtin_elementwise_fma(gp2, wg23, a23));
        h01 = __builtin_elementwise_max(h01, zero2);
        h23 = __builtin_elementwise_max(h23, zero2);
        const f32x2 ts2 = __builtin_elementwise_fma(h23, w223, h01 * w201);
        p4[mt] = ts2[0] + ts2[1];
    }
    const bool hiQ = (quad & 2) != 0;   // lane bit5
    const bool loQ = (quad & 1) != 0;   // lane bit4
    const float a  = hiQ ? p4[2] : p4[0];
    const float b  = hiQ ? p4[3] : p4[1];
    const float sa = hiQ ? p4[0] : p4[2];
    const float sb = hiQ ? p4[1] : p4[3];
    const float uA = a + swap32f(sa, hiQ);
    const float uB = b + swap32f(sb, hiQ);
    const float k  = loQ ? uB : uA;
    const float s  = loQ ? uA : uB;
    return k + swap16f(s, loQ) + b2v;
}

// ---- main fused tree kernel ----
// R26 = exact R23 structure (waves_per_eu(2), rolled loops — R24 proved
// unrolling blows the I$, R25 proved waves_per_eu(1) degrades the schedule)
// with the epilogue dot/combine and d7 leaf fold converted to packed FP32.
// Single-variable A/B vs R23's 63.1us.
__global__ __launch_bounds__(BLOCK) __attribute__((amdgpu_waves_per_eu(2)))
void tree_mfma(
    const float* __restrict__ x, const float* __restrict__ path_prob,
    const float* __restrict__ W1, const float* __restrict__ b1,
    const float* __restrict__ w2, const float* __restrict__ b2,
    const float* __restrict__ leaf_logits,
    const f16x8* __restrict__ wfrag,
    float* __restrict__ out)
{
    __shared__ float pp[128][TS];          // 32 KB: path probs, depths 3..7
    __shared__ float scbuf[127][TS];       // 31.75 KB: depth-d scores at row (2^d - 1)

    const int tid  = threadIdx.x;
    const int wv   = __builtin_amdgcn_readfirstlane(tid >> 6);
    const int l    = tid & 63;
    const int quad = l >> 4,   col = l & 15;
    const int s0   = blockIdx.x * TS;

    // x fragments (fp16): B operand B[k = t*32+quad*8+j][col]
    f16x8 xh[4][4];
    #pragma unroll
    for (int t = 0; t < 4; ++t)
        #pragma unroll
        for (int mt = 0; mt < 4; ++mt) {
            const float* xp = x + (size_t)(s0 + mt * 16 + col) * IN_DIM + t * 32 + quad * 8;
            float4 v0 = ((const float4*)xp)[0];
            float4 v1 = ((const float4*)xp)[1];
            float vv[8] = {v0.x, v0.y, v0.z, v0.w, v1.x, v1.y, v1.z, v1.w};
            f16x8 hv;
            #pragma unroll
            for (int j = 0; j < 8; ++j) hv[j] = (__fp16)vv[j];
            xh[t][mt] = hv;
        }

    // ---------------- barrier-free redundant head: d0 -> d1 -> d2 ----------------
    const int j1 = wv >> 1;                // this wave's d1 ancestor
    float sc0, sc1, sc2;
    const float z4[4] = {0.0f, 0.0f, 0.0f, 0.0f};

    {   // d0: node 0 (all waves, redundant)
        f16x8 w[4];
        loadW(wfrag, 0, l, w);
        const float4 b1q = ((const float4*)(b1))[quad];
        const float4 w2q = ((const float4*)(w2))[quad];
        const float4 wpq = ((const float4*)(W1 + 128 * 16))[quad];
        const float4 wgq = ((const float4*)(W1 + 129 * 16))[quad];
        const float  b2v = b2[0];
        f32x4 binit = {b1q.x, b1q.y, b1q.z, b1q.w};
        f32x4 acc[4] = {binit, binit, binit, binit};
        __builtin_amdgcn_s_setprio(1);
        mfma16(w, xh, acc);
        __builtin_amdgcn_s_setprio(0);
        sc0 = epi_score(acc, w2q, wpq, wgq, z4, z4, b2v, quad);
    }
    const float pp0 = path_prob[s0 + l];
    const float p0  = 1.0f / (1.0f + __expf(-sc0));
    const float pp1 = (j1 == 0) ? pp0 * p0 : pp0 * (1.0f - p0);

    float pp2;
    {   // d1: node 1 + j1 (this wave's ancestor)
        const int n = 1 + j1;
        f16x8 w[4];
        loadW(wfrag, n, l, w);
        const float4 b1q = ((const float4*)(b1 + n * 16))[quad];
        const float4 w2q = ((const float4*)(w2 + n * 16))[quad];
        const float4 wpq = ((const float4*)(W1 + (size_t)n * EFF + 128 * 16))[quad];
        const float4 wgq = ((const float4*)(W1 + (size_t)n * EFF + 129 * 16))[quad];
        const float  b2v = b2[n];
        float par[4];
        #pragma unroll
        for (int mt = 0; mt < 4; ++mt) par[mt] = __shfl(sc0, mt * 16 + col);
        f32x4 binit = {b1q.x, b1q.y, b1q.z, b1q.w};
        f32x4 acc[4] = {binit, binit, binit, binit};
        __builtin_amdgcn_s_setprio(1);
        mfma16(w, xh, acc);
        __builtin_amdgcn_s_setprio(0);
        sc1 = epi_score(acc, w2q, wpq, wgq, par, z4, b2v, quad);
        const float p = 1.0f / (1.0f + __expf(-sc1));
        pp2 = ((wv & 1) == 0) ? pp1 * p : pp1 * (1.0f - p);
    }

    {   // d2: node 3 + wv (own subtree root)
        const int n = 3 + wv;
        f16x8 w[4];
        loadW(wfrag, n, l, w);
        const float4 b1q = ((const float4*)(b1 + n * 16))[quad];
        const float4 w2q = ((const float4*)(w2 + n * 16))[quad];
        const float4 wpq = ((const float4*)(W1 + (size_t)n * EFF + 128 * 16))[quad];
        const float4 wgq = ((const float4*)(W1 + (size_t)n * EFF + 129 * 16))[quad];
        const float  b2v = b2[n];
        float par[4], gp[4];
        #pragma unroll
        for (int mt = 0; mt < 4; ++mt) {
            const int scol = mt * 16 + col;
            par[mt] = __shfl(sc1, scol);
            gp[mt]  = __shfl(sc0, scol);
        }
        f32x4 binit = {b1q.x, b1q.y, b1q.z, b1q.w};
        f32x4 acc[4] = {binit, binit, binit, binit};
        __builtin_amdgcn_s_setprio(1);
        mfma16(w, xh, acc);
        __builtin_amdgcn_s_setprio(0);
        sc2 = epi_score(acc, w2q, wpq, wgq, par, gp, b2v, quad);
        const float p = 1.0f / (1.0f + __expf(-sc2));
        // hand off to the d3+ body (sole writer per location; self-read later)
        pp[32 * wv][l]      = pp2 * p;
        pp[32 * wv + 16][l] = pp2 * (1.0f - p);
        scbuf[1 + j1][l] = sc1;            // d3 gp (benign double write, identical bits)
        scbuf[3 + wv][l] = sc2;            // d3 par + d4 gp
    }

    // ---------------- depths 3..6: pipelined node-pair iterations, wave-local ----------------
    bool   havePrev = false;
    f32x4  cAccA[4], cAccB[4];
    float4 cW2A, cW2B, cWpA, cWpB, cWgA, cWgB;
    float  cB2A = 0.f, cB2B = 0.f, cPparA = 0.f, cPparB = 0.f;
    float  cPar[4], cGp[4];
    int    cScw = 0, cSlotA = 0, cSlotB = 0, cHalf = 0;

    for (int d = 3; d < 7; ++d) {
        const int nd = 1 << d;
        const int stride = 128 >> d, half = 64 >> d;
        const int base = nd - 1, scPo = (nd >> 1) - 1, scP2o = (nd >> 2) - 1;
        const int ilo = wv * (nd >> 3), ihi = ilo + (nd >> 3);
        for (int i = ilo; i < ihi; ++i) {
            const int nA = base + 2 * i, nB = nA + 1;

            // (1) this pair's W + b1 (latency hidden under prev epilogue)
            f16x8 wA[4], wB[4];
            loadW(wfrag, nA, l, wA);
            loadW(wfrag, nB, l, wB);
            const float4 b1A = ((const float4*)(b1 + nA * 16))[quad];
            const float4 b1B = ((const float4*)(b1 + nB * 16))[quad];

            // (2) overlapped epilogue of previous pair (two independent chains)
            if (havePrev) {
                const float svA = epi_score(cAccA, cW2A, cWpA, cWgA, cPar, cGp, cB2A, quad);
                const float svB = epi_score(cAccB, cW2B, cWpB, cWgB, cPar, cGp, cB2B, quad);
                scbuf[cScw][l]     = svA;
                scbuf[cScw + 1][l] = svB;
                const float pA = 1.0f / (1.0f + __expf(-svA));
                const float pB = 1.0f / (1.0f + __expf(-svB));
                pp[cSlotA][l]         = cPparA * pA;
                pp[cSlotA + cHalf][l] = cPparA * (1.0f - pA);
                pp[cSlotB][l]         = cPparB * pB;
                pp[cSlotB + cHalf][l] = cPparB * (1.0f - pB);
            }

            // (3) this pair's epilogue scalars (consumed NEXT iteration)
            const float4 w2A = ((const float4*)(w2 + nA * 16))[quad];
            const float4 w2B = ((const float4*)(w2 + nB * 16))[quad];
            const float4 wpA = ((const float4*)(W1 + (size_t)nA * EFF + 128 * 16))[quad];
            const float4 wpB = ((const float4*)(W1 + (size_t)nB * EFF + 128 * 16))[quad];
            const float4 wgA = ((const float4*)(W1 + (size_t)nA * EFF + 129 * 16))[quad];
            const float4 wgB = ((const float4*)(W1 + (size_t)nB * EFF + 129 * 16))[quad];
            const float  b2A = b2[nA], b2B = b2[nB];
            float par[4], gp[4];                       // shared by the pair
            #pragma unroll
            for (int mt = 0; mt < 4; ++mt) {
                const int scol = mt * 16 + col;
                par[mt] = scbuf[scPo + i][scol];
                gp[mt]  = scbuf[scP2o + (i >> 1)][scol];
            }
            const int   slotA = (2 * i) * stride, slotB = slotA + stride;
            const float pparA = pp[slotA][l], pparB = pp[slotB][l];

            // (4) MFMA pair into fresh accumulators (bias folded into init)
            f32x4 iAi = {b1A.x, b1A.y, b1A.z, b1A.w};
            f32x4 iBi = {b1B.x, b1B.y, b1B.z, b1B.w};
            f32x4 accA[4] = {iAi, iAi, iAi, iAi};
            f32x4 accB[4] = {iBi, iBi, iBi, iBi};
            __builtin_amdgcn_s_setprio(1);
            mfma16(wA, xh, accA);
            mfma16(wB, xh, accB);
            __builtin_amdgcn_s_setprio(0);

            // (5) carry
            #pragma unroll
            for (int mt = 0; mt < 4; ++mt) { cAccA[mt] = accA[mt]; cAccB[mt] = accB[mt]; }
            cW2A = w2A; cW2B = w2B; cWpA = wpA; cWpB = wpB; cWgA = wgA; cWgB = wgB;
            cB2A = b2A; cB2B = b2B; cPparA = pparA; cPparB = pparB;
            #pragma unroll
            for (int mt = 0; mt < 4; ++mt) { cPar[mt] = par[mt]; cGp[mt] = gp[mt]; }
            cScw = base + 2 * i; cSlotA = slotA; cSlotB = slotB; cHalf = half;
            havePrev = true;
        }
    }
    // drain last d=6 pair
    if (havePrev) {
        const float svA = epi_score(cAccA, cW2A, cWpA, cWgA, cPar, cGp, cB2A, quad);
        const float svB = epi_score(cAccB, cW2B, cWpB, cWgB, cPar, cGp, cB2B, quad);
        scbuf[cScw][l]     = svA;
        scbuf[cScw + 1][l] = svB;
        const float pA = 1.0f / (1.0f + __expf(-svA));
        const float pB = 1.0f / (1.0f + __expf(-svB));
        pp[cSlotA][l]         = cPparA * pA;
        pp[cSlotA + cHalf][l] = cPparA * (1.0f - pA);
        pp[cSlotB][l]         = cPparB * pB;
        pp[cSlotB + cHalf][l] = cPparB * (1.0f - pB);
    }

    // ---------------- depth 7: pipelined paired leaf-mixture fold (wave-local) ----------------
    f32x2 oacc2[5];
    #pragma unroll
    for (int c2 = 0; c2 < 5; ++c2) oacc2[c2] = (f32x2){0.0f, 0.0f};
    {
        bool hp = false;
        int  cPl = 0;
        const int ilo = wv * 16, ihi = ilo + 16;
        for (int i = ilo; i < ihi; ++i) {
            const int nA = 127 + 2 * i, nB = nA + 1;

            // (1) this pair's W + b1
            f16x8 wA[4], wB[4];
            loadW(wfrag, nA, l, wA);
            loadW(wfrag, nB, l, wB);
            const float4 b1A = ((const float4*)(b1 + nA * 16))[quad];
            const float4 b1B = ((const float4*)(b1 + nB * 16))[quad];

            // (2) overlapped epilogue of previous pair; leaf rows issued first
            if (hp) {
                const float4* lp4 = (const float4*)(leaf_logits + (size_t)(4 * cPl) * NC);
                float4 lv[10];
                #pragma unroll
                for (int q = 0; q < 10; ++q) lv[q] = lp4[q];
                const float* lf = (const float*)lv;

                const float svA = epi_score(cAccA, cW2A, cWpA, cWgA, cPar, cGp, cB2A, quad);
                const float svB = epi_score(cAccB, cW2B, cWpB, cWgB, cPar, cGp, cB2B, quad);
                const float pA = 1.0f / (1.0f + __expf(-svA));
                const float pB = 1.0f / (1.0f + __expf(-svB));
                const float pLA = cPparA * pA, pRA = cPparA * (1.0f - pA);
                const float pLB = cPparB * pB, pRB = cPparB * (1.0f - pB);
                const f32x2 pLA2 = {pLA, pLA}, pRA2 = {pRA, pRA};
                const f32x2 pLB2 = {pLB, pLB}, pRB2 = {pRB, pRB};
                #pragma unroll
                for (int c2 = 0; c2 < 5; ++c2) {
                    const f32x2 lA0 = {lf[2 * c2],           lf[2 * c2 + 1]};
                    const f32x2 lA1 = {lf[NC + 2 * c2],      lf[NC + 2 * c2 + 1]};
                    const f32x2 lB0 = {lf[2 * NC + 2 * c2],  lf[2 * NC + 2 * c2 + 1]};
                    const f32x2 lB1 = {lf[3 * NC + 2 * c2],  lf[3 * NC + 2 * c2 + 1]};
                    f32x2 acc2 = __builtin_elementwise_fma(pLA2, lA0,
                                   __builtin_elementwise_fma(pRA2, lA1, oacc2[c2]));
                    acc2 = __builtin_elementwise_fma(pLB2, lB0,
                             __builtin_elementwise_fma(pRB2, lB1, acc2));
                    oacc2[c2] = acc2;
                }
            }

            // (3) this pair's epilogue scalars
            const float4 w2A = ((const float4*)(w2 + nA * 16))[quad];
            const float4 w2B = ((const float4*)(w2 + nB * 16))[quad];
            const float4 wpA = ((const float4*)(W1 + (size_t)nA * EFF + 128 * 16))[quad];
            const float4 wpB = ((const float4*)(W1 + (size_t)nB * EFF + 128 * 16))[quad];
            const float4 wgA = ((const float4*)(W1 + (size_t)nA * EFF + 129 * 16))[quad];
            const float4 wgB = ((const float4*)(W1 + (size_t)nB * EFF + 129 * 16))[quad];
            const float  b2A = b2[nA], b2B = b2[nB];
            float par[4], gp[4];
            #pragma unroll
            for (int mt = 0; mt < 4; ++mt) {
                const int scol = mt * 16 + col;
                par[mt] = scbuf[63 + i][scol];
                gp[mt]  = scbuf[31 + (i >> 1)][scol];
            }
            const float pparA = pp[2 * i][l], pparB = pp[2 * i + 1][l];

            // (4) MFMA
            f32x4 iAi = {b1A.x, b1A.y, b1A.z, b1A.w};
            f32x4 iBi = {b1B.x, b1B.y, b1B.z, b1B.w};
            f32x4 accA[4] = {iAi, iAi, iAi, iAi};
            f32x4 accB[4] = {iBi, iBi, iBi, iBi};
            __builtin_amdgcn_s_setprio(1);
            mfma16(wA, xh, accA);
            mfma16(wB, xh, accB);
            __builtin_amdgcn_s_setprio(0);

            // (5) carry
            #pragma unroll
            for (int mt = 0; mt < 4; ++mt) { cAccA[mt] = accA[mt]; cAccB[mt] = accB[mt]; }
            cW2A = w2A; cW2B = w2B; cWpA = wpA; cWpB = wpB; cWgA = wgA; cWgB = wgB;
            cB2A = b2A; cB2B = b2B; cPparA = pparA; cPparB = pparB;
            #pragma unroll
            for (int mt = 0; mt < 4; ++mt) { cPar[mt] = par[mt]; cGp[mt] = gp[mt]; }
            cPl = i;
            hp = true;
        }
        // drain last leaf pair
        if (hp) {
            const float4* lp4 = (const float4*)(leaf_logits + (size_t)(4 * cPl) * NC);
            float4 lv[10];
            #pragma unroll
            for (int q = 0; q < 10; ++q) lv[q] = lp4[q];
            const float* lf = (const float*)lv;

            const float svA = epi_score(cAccA, cW2A, cWpA, cWgA, cPar, cGp, cB2A, quad);
            const float svB = epi_score(cAccB, cW2B, cWpB, cWgB, cPar, cGp, cB2B, quad);
            const float pA = 1.0f / (1.0f + __expf(-svA));
            const float pB = 1.0f / (1.0f + __expf(-svB));
            const float pLA = cPparA * pA, pRA = cPparA * (1.0f - pA);
            const float pLB = cPparB * pB, pRB = cPparB * (1.0f - pB);
            const f32x2 pLA2 = {pLA, pLA}, pRA2 = {pRA, pRA};
            const f32x2 pLB2 = {pLB, pLB}, pRB2 = {pRB, pRB};
            #pragma unroll
            for (int c2 = 0; c2 < 5; ++c2) {
                const f32x2 lA0 = {lf[2 * c2],           lf[2 * c2 + 1]};
                const f32x2 lA1 = {lf[NC + 2 * c2],      lf[NC + 2 * c2 + 1]};
                const f32x2 lB0 = {lf[2 * NC + 2 * c2],  lf[2 * NC + 2 * c2 + 1]};
                const f32x2 lB1 = {lf[3 * NC + 2 * c2],  lf[3 * NC + 2 * c2 + 1]};
                f32x2 acc2 = __builtin_elementwise_fma(pLA2, lA0,
                               __builtin_elementwise_fma(pRA2, lA1, oacc2[c2]));
                acc2 = __builtin_elementwise_fma(pLB2, lB0,
                         __builtin_elementwise_fma(pRB2, lB1, acc2));
                oacc2[c2] = acc2;
            }
        }
    }

    // ---------------- cross-wave out reduction through scbuf ----------------
    __syncthreads();
    {
        float* red = &scbuf[0][0];         // 4*64*10 = 2560 floats <= 8128
        #pragma unroll
        for (int c = 0; c < NC; ++c)
            red[(wv * 64 + l) * NC + c] = oacc2[c >> 1][c & 1];
    }
    __syncthreads();
    {
        const float* red = &scbuf[0][0];
        for (int i = tid; i < TS * NC; i += BLOCK) {
            float v = red[i] + red[640 + i] + red[1280 + i] + red[1920 + i];
            out[(size_t)s0 * NC + i] = v;
        }
    }
}

} // namespace

extern "C" void kernel_launch(void* const* d_in, const int* in_sizes, int n_in,
                              void* d_out, int out_size, void* d_ws, size_t ws_size,
                              hipStream_t stream) {
    const float* x           = (const float*)d_in[0];
    const float* path_prob   = (const float*)d_in[1];
    const float* W1          = (const float*)d_in[2];
    const float* b1          = (const float*)d_in[3];
    const float* w2          = (const float*)d_in[4];
    const float* b2          = (const float*)d_in[5];
    const float* leaf_logits = (const float*)d_in[6];
    float* out = (float*)d_out;

    const int batch = in_sizes[0] / IN_DIM;                // 32768
    f16x8* wfrag = (f16x8*)d_ws;                           // 255*4*64*16B ~= 1.04 MB

    hipLaunchKernelGGL(prep_w1, dim3(NODES), dim3(256), 0, stream, W1, wfrag);
    hipLaunchKernelGGL(tree_mfma, dim3(batch / TS), dim3(BLOCK), 0, stream,
                       x, path_prob, W1, b1, w2, b2, leaf_logits, wfrag, out);
}

// Round 12
// 127.617 us; speedup vs baseline: 1.0278x; 1.0278x over previous
//
#include <hip/hip_runtime.h>
#include <math.h>

namespace {

typedef __attribute__((ext_vector_type(8))) __fp16 f16x8;
typedef __attribute__((ext_vector_type(4))) float f32x4;

constexpr int IN_DIM = 128;
constexpr int EFF    = 130 * 16;   // W1 node stride (floats)
constexpr int NODES  = 255;
constexpr int TS     = 64;         // samples per block (4 MFMA N-tiles per wave)
constexpr int BLOCK  = 256;
constexpr int NC     = 10;

// ---- prep: W1[:, :128, :] -> MFMA fragment layout, fp16 (single product) ----
// frag element (n, t, lane l, j): W[k = t*32 + (l>>4)*8 + j][hid = l&15]
__global__ __launch_bounds__(256) void prep_w1(const float* __restrict__ W1,
                                               f16x8* __restrict__ wfrag) {
    __shared__ float xs[IN_DIM * 16];      // 8 KB: rows 0..127 of this node
    const int n = blockIdx.x, tid = threadIdx.x;
    const float4* src = (const float4*)(W1 + (size_t)n * EFF);
    ((float4*)xs)[tid]       = src[tid];
    ((float4*)xs)[tid + 256] = src[tid + 256];
    __syncthreads();
    const int l = tid & 63, t = tid >> 6;
    const int k0 = t * 32 + (l >> 4) * 8, hid = l & 15;
    f16x8 hv;
    #pragma unroll
    for (int j = 0; j < 8; ++j)
        hv[j] = (__fp16)xs[(k0 + j) * 16 + hid];   // RNE
    wfrag[(n * 4 + t) * 64 + l] = hv;
}

__device__ __forceinline__ void loadW(const f16x8* __restrict__ wfrag, int n, int l,
                                      f16x8 (&w)[4]) {
    const f16x8* wp = wfrag + (size_t)n * 256 + l;
    #pragma unroll
    for (int t = 0; t < 4; ++t) w[t] = wp[t * 64];
}

__device__ __forceinline__ void mfma16(const f16x8 (&w)[4], const f16x8 (&xh)[4][4],
                                       f32x4 (&acc)[4]) {
    #pragma unroll
    for (int t = 0; t < 4; ++t)
        #pragma unroll
        for (int mt = 0; mt < 4; ++mt)
            acc[mt] = __builtin_amdgcn_mfma_f32_16x16x32_f16(w[t], xh[t][mt], acc[mt], 0, 0, 0);
}

#define COMP4(v, r) ((r == 0) ? v.x : (r == 1) ? v.y : (r == 2) ? v.z : v.w)

// combine + hid-reduce, butterfly reduce-scatter (3 shfl + 3 add + 6 selects).
// Scalar fp32 form is deliberate: R26 proved packed (f32x2) variants reduce
// issue count but LENGTHEN the schedule (fewer independent chains) — slower.
__device__ __forceinline__ float epi_score(
    const f32x4 (&acc)[4], const float4& w2q, const float4& wpq, const float4& wgq,
    const float (&par)[4], const float (&gp)[4], float b2v, int quad)
{
    float p4[4];
    #pragma unroll
    for (int mt = 0; mt < 4; ++mt) {
        float ts = 0.0f;
        #pragma unroll
        for (int r = 0; r < 4; ++r) {
            const float wpr = COMP4(wpq, r);
            const float wgr = COMP4(wgq, r);
            const float w2r = COMP4(w2q, r);
            const float h = fmaf(par[mt], wpr, fmaf(gp[mt], wgr, acc[mt][r]));
            ts = fmaf(fmaxf(h, 0.0f), w2r, ts);
        }
        p4[mt] = ts;
    }
    const bool hiQ = (quad & 2) != 0;
    const bool loQ = (quad & 1) != 0;
    const float a  = hiQ ? p4[2] : p4[0];
    const float b  = hiQ ? p4[3] : p4[1];
    const float sa = hiQ ? p4[0] : p4[2];
    const float sb = hiQ ? p4[1] : p4[3];
    const float uA = a + __shfl_xor(sa, 32);
    const float uB = b + __shfl_xor(sb, 32);
    const float k  = loQ ? uB : uA;
    const float s  = loQ ? uA : uB;
    return k + __shfl_xor(s, 16) + b2v;
}

// ---- main fused tree kernel ----
// R27 = exact R22, the session's best-measured variant (62.8-63.5us kernel).
// Locked-in structure and the falsification ledger that protects it:
//  - TS=64 / BLOCK=256 / waves_per_eu(2): occupancy is grid+LDS-pinned at
//    2 blocks/CU = 8 waves/CU; every other shape regressed (R16-R18), and
//    loosening the 128-VGPR cap degrades the schedule (R25: 74us).
//  - Rolled loops: unrolling replicates the ~large pair body past the 32KB
//    I$ (R24: 103-113us, VALUBusy 48->29 with no spills).
//  - Pipelined node-PAIR body (R21): prev-pair epilogue overlapped with this
//    pair's loads+MFMA; two independent epilogue chains fill each other's
//    dependency bubbles. Removing the pipeline costs 4% (R20); W-prefetch
//    beyond 1 iteration costs 14% (R19).
//  - Barrier-free redundant head (R22): every wave computes node0 ->
//    node(1+(wv>>1)) -> node(3+wv) with par/gp via __shfl of its own regs;
//    zero barriers until the output reduction. setprio(1) around MFMA
//    bursts; readfirstlane(wv) for SGPR addressing. (+9% bundle, R22.)
//  - Scalar fp32 epilogue + __shfl_xor butterfly: permlane swap (R23) was
//    neutral-to-slightly-negative; packed f32 (R26) was -7%; issue-count
//    reductions do not convert to time in this latency-bound regime.
// Remaining ~30% all-wave idle is structural: 31 serial pair-iterations,
// dependency-limited, at 2 waves/SIMD with no third block available.
__global__ __launch_bounds__(BLOCK) __attribute__((amdgpu_waves_per_eu(2)))
void tree_mfma(
    const float* __restrict__ x, const float* __restrict__ path_prob,
    const float* __restrict__ W1, const float* __restrict__ b1,
    const float* __restrict__ w2, const float* __restrict__ b2,
    const float* __restrict__ leaf_logits,
    const f16x8* __restrict__ wfrag,
    float* __restrict__ out)
{
    __shared__ float pp[128][TS];          // 32 KB: path probs, depths 3..7
    __shared__ float scbuf[127][TS];       // 31.75 KB: depth-d scores at row (2^d - 1)

    const int tid  = threadIdx.x;
    const int wv   = __builtin_amdgcn_readfirstlane(tid >> 6);
    const int l    = tid & 63;
    const int quad = l >> 4,   col = l & 15;
    const int s0   = blockIdx.x * TS;

    // x fragments (fp16): B operand B[k = t*32+quad*8+j][col]
    f16x8 xh[4][4];
    #pragma unroll
    for (int t = 0; t < 4; ++t)
        #pragma unroll
        for (int mt = 0; mt < 4; ++mt) {
            const float* xp = x + (size_t)(s0 + mt * 16 + col) * IN_DIM + t * 32 + quad * 8;
            float4 v0 = ((const float4*)xp)[0];
            float4 v1 = ((const float4*)xp)[1];
            float vv[8] = {v0.x, v0.y, v0.z, v0.w, v1.x, v1.y, v1.z, v1.w};
            f16x8 hv;
            #pragma unroll
            for (int j = 0; j < 8; ++j) hv[j] = (__fp16)vv[j];
            xh[t][mt] = hv;
        }

    // ---------------- barrier-free redundant head: d0 -> d1 -> d2 ----------------
    const int j1 = wv >> 1;                // this wave's d1 ancestor
    float sc0, sc1, sc2;
    const float z4[4] = {0.0f, 0.0f, 0.0f, 0.0f};

    {   // d0: node 0 (all waves, redundant)
        f16x8 w[4];
        loadW(wfrag, 0, l, w);
        const float4 b1q = ((const float4*)(b1))[quad];
        const float4 w2q = ((const float4*)(w2))[quad];
        const float4 wpq = ((const float4*)(W1 + 128 * 16))[quad];
        const float4 wgq = ((const float4*)(W1 + 129 * 16))[quad];
        const float  b2v = b2[0];
        f32x4 binit = {b1q.x, b1q.y, b1q.z, b1q.w};
        f32x4 acc[4] = {binit, binit, binit, binit};
        __builtin_amdgcn_s_setprio(1);
        mfma16(w, xh, acc);
        __builtin_amdgcn_s_setprio(0);
        sc0 = epi_score(acc, w2q, wpq, wgq, z4, z4, b2v, quad);
    }
    const float pp0 = path_prob[s0 + l];
    const float p0  = 1.0f / (1.0f + __expf(-sc0));
    const float pp1 = (j1 == 0) ? pp0 * p0 : pp0 * (1.0f - p0);

    float pp2;
    {   // d1: node 1 + j1 (this wave's ancestor)
        const int n = 1 + j1;
        f16x8 w[4];
        loadW(wfrag, n, l, w);
        const float4 b1q = ((const float4*)(b1 + n * 16))[quad];
        const float4 w2q = ((const float4*)(w2 + n * 16))[quad];
        const float4 wpq = ((const float4*)(W1 + (size_t)n * EFF + 128 * 16))[quad];
        const float4 wgq = ((const float4*)(W1 + (size_t)n * EFF + 129 * 16))[quad];
        const float  b2v = b2[n];
        float par[4];
        #pragma unroll
        for (int mt = 0; mt < 4; ++mt) par[mt] = __shfl(sc0, mt * 16 + col);
        f32x4 binit = {b1q.x, b1q.y, b1q.z, b1q.w};
        f32x4 acc[4] = {binit, binit, binit, binit};
        __builtin_amdgcn_s_setprio(1);
        mfma16(w, xh, acc);
        __builtin_amdgcn_s_setprio(0);
        sc1 = epi_score(acc, w2q, wpq, wgq, par, z4, b2v, quad);
        const float p = 1.0f / (1.0f + __expf(-sc1));
        pp2 = ((wv & 1) == 0) ? pp1 * p : pp1 * (1.0f - p);
    }

    {   // d2: node 3 + wv (own subtree root)
        const int n = 3 + wv;
        f16x8 w[4];
        loadW(wfrag, n, l, w);
        const float4 b1q = ((const float4*)(b1 + n * 16))[quad];
        const float4 w2q = ((const float4*)(w2 + n * 16))[quad];
        const float4 wpq = ((const float4*)(W1 + (size_t)n * EFF + 128 * 16))[quad];
        const float4 wgq = ((const float4*)(W1 + (size_t)n * EFF + 129 * 16))[quad];
        const float  b2v = b2[n];
        float par[4], gp[4];
        #pragma unroll
        for (int mt = 0; mt < 4; ++mt) {
            const int scol = mt * 16 + col;
            par[mt] = __shfl(sc1, scol);
            gp[mt]  = __shfl(sc0, scol);
        }
        f32x4 binit = {b1q.x, b1q.y, b1q.z, b1q.w};
        f32x4 acc[4] = {binit, binit, binit, binit};
        __builtin_amdgcn_s_setprio(1);
        mfma16(w, xh, acc);
        __builtin_amdgcn_s_setprio(0);
        sc2 = epi_score(acc, w2q, wpq, wgq, par, gp, b2v, quad);
        const float p = 1.0f / (1.0f + __expf(-sc2));
        // hand off to the d3+ body (sole writer per location; self-read later)
        pp[32 * wv][l]      = pp2 * p;
        pp[32 * wv + 16][l] = pp2 * (1.0f - p);
        scbuf[1 + j1][l] = sc1;            // d3 gp (benign double write, identical bits)
        scbuf[3 + wv][l] = sc2;            // d3 par + d4 gp
    }

    // ---------------- depths 3..6: pipelined node-pair iterations, wave-local ----------------
    bool   havePrev = false;
    f32x4  cAccA[4], cAccB[4];
    float4 cW2A, cW2B, cWpA, cWpB, cWgA, cWgB;
    float  cB2A = 0.f, cB2B = 0.f, cPparA = 0.f, cPparB = 0.f;
    float  cPar[4], cGp[4];
    int    cScw = 0, cSlotA = 0, cSlotB = 0, cHalf = 0;

    for (int d = 3; d < 7; ++d) {
        const int nd = 1 << d;
        const int stride = 128 >> d, half = 64 >> d;
        const int base = nd - 1, scPo = (nd >> 1) - 1, scP2o = (nd >> 2) - 1;
        const int ilo = wv * (nd >> 3), ihi = ilo + (nd >> 3);
        for (int i = ilo; i < ihi; ++i) {
            const int nA = base + 2 * i, nB = nA + 1;

            // (1) this pair's W + b1 (latency hidden under prev epilogue)
            f16x8 wA[4], wB[4];
            loadW(wfrag, nA, l, wA);
            loadW(wfrag, nB, l, wB);
            const float4 b1A = ((const float4*)(b1 + nA * 16))[quad];
            const float4 b1B = ((const float4*)(b1 + nB * 16))[quad];

            // (2) overlapped epilogue of previous pair (two independent chains)
            if (havePrev) {
                const float svA = epi_score(cAccA, cW2A, cWpA, cWgA, cPar, cGp, cB2A, quad);
                const float svB = epi_score(cAccB, cW2B, cWpB, cWgB, cPar, cGp, cB2B, quad);
                scbuf[cScw][l]     = svA;
                scbuf[cScw + 1][l] = svB;
                const float pA = 1.0f / (1.0f + __expf(-svA));
                const float pB = 1.0f / (1.0f + __expf(-svB));
                pp[cSlotA][l]         = cPparA * pA;
                pp[cSlotA + cHalf][l] = cPparA * (1.0f - pA);
                pp[cSlotB][l]         = cPparB * pB;
                pp[cSlotB + cHalf][l] = cPparB * (1.0f - pB);
            }

            // (3) this pair's epilogue scalars (consumed NEXT iteration)
            const float4 w2A = ((const float4*)(w2 + nA * 16))[quad];
            const float4 w2B = ((const float4*)(w2 + nB * 16))[quad];
            const float4 wpA = ((const float4*)(W1 + (size_t)nA * EFF + 128 * 16))[quad];
            const float4 wpB = ((const float4*)(W1 + (size_t)nB * EFF + 128 * 16))[quad];
            const float4 wgA = ((const float4*)(W1 + (size_t)nA * EFF + 129 * 16))[quad];
            const float4 wgB = ((const float4*)(W1 + (size_t)nB * EFF + 129 * 16))[quad];
            const float  b2A = b2[nA], b2B = b2[nB];
            float par[4], gp[4];                       // shared by the pair
            #pragma unroll
            for (int mt = 0; mt < 4; ++mt) {
                const int scol = mt * 16 + col;
                par[mt] = scbuf[scPo + i][scol];
                gp[mt]  = scbuf[scP2o + (i >> 1)][scol];
            }
            const int   slotA = (2 * i) * stride, slotB = slotA + stride;
            const float pparA = pp[slotA][l], pparB = pp[slotB][l];

            // (4) MFMA pair into fresh accumulators (bias folded into init)
            f32x4 iAi = {b1A.x, b1A.y, b1A.z, b1A.w};
            f32x4 iBi = {b1B.x, b1B.y, b1B.z, b1B.w};
            f32x4 accA[4] = {iAi, iAi, iAi, iAi};
            f32x4 accB[4] = {iBi, iBi, iBi, iBi};
            __builtin_amdgcn_s_setprio(1);
            mfma16(wA, xh, accA);
            mfma16(wB, xh, accB);
            __builtin_amdgcn_s_setprio(0);

            // (5) carry
            #pragma unroll
            for (int mt = 0; mt < 4; ++mt) { cAccA[mt] = accA[mt]; cAccB[mt] = accB[mt]; }
            cW2A = w2A; cW2B = w2B; cWpA = wpA; cWpB = wpB; cWgA = wgA; cWgB = wgB;
            cB2A = b2A; cB2B = b2B; cPparA = pparA; cPparB = pparB;
            #pragma unroll
            for (int mt = 0; mt < 4; ++mt) { cPar[mt] = par[mt]; cGp[mt] = gp[mt]; }
            cScw = base + 2 * i; cSlotA = slotA; cSlotB = slotB; cHalf = half;
            havePrev = true;
        }
    }
    // drain last d=6 pair
    if (havePrev) {
        const float svA = epi_score(cAccA, cW2A, cWpA, cWgA, cPar, cGp, cB2A, quad);
        const float svB = epi_score(cAccB, cW2B, cWpB, cWgB, cPar, cGp, cB2B, quad);
        scbuf[cScw][l]     = svA;
        scbuf[cScw + 1][l] = svB;
        const float pA = 1.0f / (1.0f + __expf(-svA));
        const float pB = 1.0f / (1.0f + __expf(-svB));
        pp[cSlotA][l]         = cPparA * pA;
        pp[cSlotA + cHalf][l] = cPparA * (1.0f - pA);
        pp[cSlotB][l]         = cPparB * pB;
        pp[cSlotB + cHalf][l] = cPparB * (1.0f - pB);
    }

    // ---------------- depth 7: pipelined paired leaf-mixture fold (wave-local) ----------------
    float oacc[NC];
    #pragma unroll
    for (int c = 0; c < NC; ++c) oacc[c] = 0.0f;
    {
        bool hp = false;
        int  cPl = 0;
        const int ilo = wv * 16, ihi = ilo + 16;
        for (int i = ilo; i < ihi; ++i) {
            const int nA = 127 + 2 * i, nB = nA + 1;

            // (1) this pair's W + b1
            f16x8 wA[4], wB[4];
            loadW(wfrag, nA, l, wA);
            loadW(wfrag, nB, l, wB);
            const float4 b1A = ((const float4*)(b1 + nA * 16))[quad];
            const float4 b1B = ((const float4*)(b1 + nB * 16))[quad];

            // (2) overlapped epilogue of previous pair; leaf rows issued first
            if (hp) {
                const float4* lp4 = (const float4*)(leaf_logits + (size_t)(4 * cPl) * NC);
                float4 lv[10];
                #pragma unroll
                for (int q = 0; q < 10; ++q) lv[q] = lp4[q];
                const float* lf = (const float*)lv;

                const float svA = epi_score(cAccA, cW2A, cWpA, cWgA, cPar, cGp, cB2A, quad);
                const float svB = epi_score(cAccB, cW2B, cWpB, cWgB, cPar, cGp, cB2B, quad);
                const float pA = 1.0f / (1.0f + __expf(-svA));
                const float pB = 1.0f / (1.0f + __expf(-svB));
                const float pLA = cPparA * pA, pRA = cPparA * (1.0f - pA);
                const float pLB = cPparB * pB, pRB = cPparB * (1.0f - pB);
                #pragma unroll
                for (int c = 0; c < NC; ++c)
                    oacc[c] = fmaf(pLA, lf[c], fmaf(pRA, lf[NC + c], oacc[c]));
                #pragma unroll
                for (int c = 0; c < NC; ++c)
                    oacc[c] = fmaf(pLB, lf[2 * NC + c], fmaf(pRB, lf[3 * NC + c], oacc[c]));
            }

            // (3) this pair's epilogue scalars
            const float4 w2A = ((const float4*)(w2 + nA * 16))[quad];
            const float4 w2B = ((const float4*)(w2 + nB * 16))[quad];
            const float4 wpA = ((const float4*)(W1 + (size_t)nA * EFF + 128 * 16))[quad];
            const float4 wpB = ((const float4*)(W1 + (size_t)nB * EFF + 128 * 16))[quad];
            const float4 wgA = ((const float4*)(W1 + (size_t)nA * EFF + 129 * 16))[quad];
            const float4 wgB = ((const float4*)(W1 + (size_t)nB * EFF + 129 * 16))[quad];
            const float  b2A = b2[nA], b2B = b2[nB];
            float par[4], gp[4];
            #pragma unroll
            for (int mt = 0; mt < 4; ++mt) {
                const int scol = mt * 16 + col;
                par[mt] = scbuf[63 + i][scol];
                gp[mt]  = scbuf[31 + (i >> 1)][scol];
            }
            const float pparA = pp[2 * i][l], pparB = pp[2 * i + 1][l];

            // (4) MFMA
            f32x4 iAi = {b1A.x, b1A.y, b1A.z, b1A.w};
            f32x4 iBi = {b1B.x, b1B.y, b1B.z, b1B.w};
            f32x4 accA[4] = {iAi, iAi, iAi, iAi};
            f32x4 accB[4] = {iBi, iBi, iBi, iBi};
            __builtin_amdgcn_s_setprio(1);
            mfma16(wA, xh, accA);
            mfma16(wB, xh, accB);
            __builtin_amdgcn_s_setprio(0);

            // (5) carry
            #pragma unroll
            for (int mt = 0; mt < 4; ++mt) { cAccA[mt] = accA[mt]; cAccB[mt] = accB[mt]; }
            cW2A = w2A; cW2B = w2B; cWpA = wpA; cWpB = wpB; cWgA = wgA; cWgB = wgB;
            cB2A = b2A; cB2B = b2B; cPparA = pparA; cPparB = pparB;
            #pragma unroll
            for (int mt = 0; mt < 4; ++mt) { cPar[mt] = par[mt]; cGp[mt] = gp[mt]; }
            cPl = i;
            hp = true;
        }
        // drain last leaf pair
        if (hp) {
            const float4* lp4 = (const float4*)(leaf_logits + (size_t)(4 * cPl) * NC);
            float4 lv[10];
            #pragma unroll
            for (int q = 0; q < 10; ++q) lv[q] = lp4[q];
            const float* lf = (const float*)lv;

            const float svA = epi_score(cAccA, cW2A, cWpA, cWgA, cPar, cGp, cB2A, quad);
            const float svB = epi_score(cAccB, cW2B, cWpB, cWgB, cPar, cGp, cB2B, quad);
            const float pA = 1.0f / (1.0f + __expf(-svA));
            const float pB = 1.0f / (1.0f + __expf(-svB));
            const float pLA = cPparA * pA, pRA = cPparA * (1.0f - pA);
            const float pLB = cPparB * pB, pRB = cPparB * (1.0f - pB);
            #pragma unroll
            for (int c = 0; c < NC; ++c)
                oacc[c] = fmaf(pLA, lf[c], fmaf(pRA, lf[NC + c], oacc[c]));
            #pragma unroll
            for (int c = 0; c < NC; ++c)
                oacc[c] = fmaf(pLB, lf[2 * NC + c], fmaf(pRB, lf[3 * NC + c], oacc[c]));
        }
    }

    // ---------------- cross-wave out reduction through scbuf ----------------
    __syncthreads();
    {
        float* red = &scbuf[0][0];         // 4*64*10 = 2560 floats <= 8128
        #pragma unroll
        for (int c = 0; c < NC; ++c)
            red[(wv * 64 + l) * NC + c] = oacc[c];
    }
    __syncthreads();
    {
        const float* red = &scbuf[0][0];
        for (int i = tid; i < TS * NC; i += BLOCK) {
            float v = red[i] + red[640 + i] + red[1280 + i] + red[1920 + i];
            out[(size_t)s0 * NC + i] = v;
        }
    }
}

} // namespace

extern "C" void kernel_launch(void* const* d_in, const int* in_sizes, int n_in,
                              void* d_out, int out_size, void* d_ws, size_t ws_size,
                              hipStream_t stream) {
    const float* x           = (const float*)d_in[0];
    const float* path_prob   = (const float*)d_in[1];
    const float* W1          = (const float*)d_in[2];
    const float* b1          = (const float*)d_in[3];
    const float* w2          = (const float*)d_in[4];
    const float* b2          = (const float*)d_in[5];
    const float* leaf_logits = (const float*)d_in[6];
    float* out = (float*)d_out;

    const int batch = in_sizes[0] / IN_DIM;                // 32768
    f16x8* wfrag = (f16x8*)d_ws;                           // 255*4*64*16B ~= 1.04 MB

    hipLaunchKernelGGL(prep_w1, dim3(NODES), dim3(256), 0, stream, W1, wfrag);
    hipLaunchKernelGGL(tree_mfma, dim3(batch / TS), dim3(BLOCK), 0, stream,
                       x, path_prob, W1, b1, w2, b2, leaf_logits, wfrag, out);
}